// Round 2
// baseline (185.437 us; speedup 1.0000x reference)
//
#include <hip/hip_runtime.h>
#include <math.h>

// MutualInformationLoss: binary 256x256 occupancy map -> MI -> 1 - tanh(mi).
// R2: latency-bound fix — 1024x512 grid (100% occupancy cap), unroll-3 load
// pairs for MLP; finalize fused into hist via last-block-done (saves a launch).

#define NB 256
#define BM_WORDS 2048   // 65536 bins / 32 bits; word BM_WORDS is the arrival counter

__global__ void zero_kernel(unsigned int* __restrict__ bm) {
    int i = blockIdx.x * blockDim.x + threadIdx.x;
    if (i < BM_WORDS + 1) bm[i] = 0u;
}

__device__ __forceinline__ void set_bin(unsigned int* bm, float a, float b) {
    // Exact replica of jnp: clip(x*255, 0, 255).astype(int32) (truncation).
    float va = fminf(fmaxf(a * 255.0f, 0.0f), 255.0f);
    float vb = fminf(fmaxf(b * 255.0f, 0.0f), 255.0f);
    int bin = ((int)va << 8) | (int)vb;
    atomicOr(&bm[bin >> 5], 1u << (bin & 31));
}

__global__ __launch_bounds__(512, 2) void hist_kernel(const float* __restrict__ x,
                                                      const float* __restrict__ y,
                                                      unsigned int* __restrict__ gbm,
                                                      float* __restrict__ out,
                                                      int n) {
    __shared__ unsigned int bm[BM_WORDS];
    __shared__ float rcs[NB];
    __shared__ float red[8];
    __shared__ unsigned int ticket;
    const int t = threadIdx.x;

    for (int k = t; k < BM_WORDS; k += blockDim.x) bm[k] = 0u;
    __syncthreads();

    const int n4 = n >> 2;
    const float4* __restrict__ x4 = (const float4*)x;
    const float4* __restrict__ y4 = (const float4*)y;
    const int nth = gridDim.x * blockDim.x;
    int i = blockIdx.x * blockDim.x + t;

    // Unroll-3: issue 6 independent float4 loads before any wait (MLP).
    for (; i + 2 * nth < n4; i += 3 * nth) {
        float4 a0 = x4[i];           float4 b0 = y4[i];
        float4 a1 = x4[i + nth];     float4 b1 = y4[i + nth];
        float4 a2 = x4[i + 2 * nth]; float4 b2 = y4[i + 2 * nth];
        set_bin(bm, a0.x, b0.x); set_bin(bm, a0.y, b0.y);
        set_bin(bm, a0.z, b0.z); set_bin(bm, a0.w, b0.w);
        set_bin(bm, a1.x, b1.x); set_bin(bm, a1.y, b1.y);
        set_bin(bm, a1.z, b1.z); set_bin(bm, a1.w, b1.w);
        set_bin(bm, a2.x, b2.x); set_bin(bm, a2.y, b2.y);
        set_bin(bm, a2.z, b2.z); set_bin(bm, a2.w, b2.w);
    }
    for (; i < n4; i += nth) {
        float4 a = x4[i]; float4 b = y4[i];
        set_bin(bm, a.x, b.x); set_bin(bm, a.y, b.y);
        set_bin(bm, a.z, b.z); set_bin(bm, a.w, b.w);
    }
    // scalar tail (n % 4)
    for (int j = (n4 << 2) + blockIdx.x * blockDim.x + t; j < n; j += nth) {
        set_bin(bm, x[j], y[j]);
    }
    __syncthreads();

    // Merge into global bitmap. Racy pre-read skip is safe: bits are monotone,
    // a stale read only causes an extra (idempotent) atomicOr.
    for (int k = t; k < BM_WORDS; k += blockDim.x) {
        unsigned int v = bm[k];
        if (v) {
            unsigned int g = gbm[k];
            if (v & ~g) atomicOr(&gbm[k], v);
        }
    }
    __syncthreads();

    // Last-block-done: arrival counter with release/acquire fencing.
    if (t == 0) {
        __threadfence();  // release our merges before the ticket
        ticket = __hip_atomic_fetch_add(&gbm[BM_WORDS], 1u, __ATOMIC_ACQ_REL,
                                        __HIP_MEMORY_SCOPE_AGENT);
    }
    __syncthreads();
    if (ticket != gridDim.x - 1) return;

    // ---- finalize (last block only) ----
    __threadfence();  // acquire all other blocks' merges
    for (int k = t; k < BM_WORDS; k += blockDim.x)
        bm[k] = __hip_atomic_load(&gbm[k], __ATOMIC_RELAXED, __HIP_MEMORY_SCOPE_AGENT);
    __syncthreads();

    float partial = 0.0f;
    int r = 0, c = 0;
    if (t < NB) {
        // Row count for row t: words [t*8, t*8+8)
#pragma unroll
        for (int k = 0; k < 8; ++k) r += __popc(bm[t * 8 + k]);
        rcs[t] = (float)r;
        // Column count for column t: bit (t&31) of word i*8 + (t>>5), rows i
        const int wsel = t >> 5;
        const int bsel = t & 31;
        for (int i2 = 0; i2 < NB; ++i2) c += (bm[i2 * 8 + wsel] >> bsel) & 1;
    }
    __syncthreads();

    float S = 0.0f;
    if (t < NB) {
        for (int i2 = 0; i2 < NB; ++i2) S += rcs[i2];
        // mi = -log(S) - ( sum_i rc_i*log(rc_i/S) + sum_j cc_j*log(cc_j/S) ) / S
        // (eps=1e-10 in the reference denom perturbs mi by <1e-5; << 2e-2 tol)
        if (r > 0) partial += (float)r * logf((float)r / S);
        if (c > 0) partial += (float)c * logf((float)c / S);
        for (int off = 32; off > 0; off >>= 1) partial += __shfl_down(partial, off, 64);
        if ((t & 63) == 0) red[t >> 6] = partial;
    }
    __syncthreads();
    if (t == 0) {
        float B = red[0] + red[1] + red[2] + red[3];
        float mi = -logf(S) - B / S;
        out[0] = 1.0f - tanhf(mi);
    }
}

extern "C" void kernel_launch(void* const* d_in, const int* in_sizes, int n_in,
                              void* d_out, int out_size, void* d_ws, size_t ws_size,
                              hipStream_t stream) {
    const float* x = (const float*)d_in[0];  // I_complementary -> row bins
    const float* y = (const float*)d_in[1];  // I_target        -> col bins
    float* out = (float*)d_out;
    unsigned int* gbm = (unsigned int*)d_ws;  // 8 KB bitmap + 4 B counter
    const int n = in_sizes[0];

    zero_kernel<<<(BM_WORDS + 1 + 255) / 256, 256, 0, stream>>>(gbm);
    hist_kernel<<<1024, 512, 0, stream>>>(x, y, gbm, out, n);
}

// Round 3
// 125.043 us; speedup vs baseline: 1.4830x; 1.4830x over previous
//
#include <hip/hip_runtime.h>
#include <math.h>

// MutualInformationLoss: binary 256x256 occupancy map -> MI -> 1 - tanh(mi).
// R3: kill the contended global-atomicOr merge (R1/R2 bottleneck: ~1-2M
// device-scope atomics onto 128 cache lines). Each hist block now writes its
// private bitmap to its own 8KB slice (plain uint4 stores); a 64-block reduce
// kernel OR-combines slices and finalizes via last-block-done.

#define NB 256
#define BM_WORDS 2048          // 65536 bins / 32
#define HGRID 512
#define HTHREADS 512
#define RGRID 64
#define RTHREADS 256

// ws layout (main path, words): [0, HGRID*BM_WORDS) slices,
// [SL, SL+BM_WORDS) final bitmap, [SL+BM_WORDS] arrival counter.
#define SL_WORDS (HGRID * BM_WORDS)

__device__ __forceinline__ void set_bin(unsigned int* bm, float a, float b) {
    // Exact replica of jnp: clip(x*255, 0, 255).astype(int32) (truncation).
    float va = fminf(fmaxf(a * 255.0f, 0.0f), 255.0f);
    float vb = fminf(fmaxf(b * 255.0f, 0.0f), 255.0f);
    int bin = ((int)va << 8) | (int)vb;
    atomicOr(&bm[bin >> 5], 1u << (bin & 31));
}

__device__ __forceinline__ void finalize_from_lds(unsigned int* w, float* rcs, float* red,
                                                  int t, float* out) {
    float partial = 0.0f;
    int r = 0, c = 0;
    if (t < NB) {
        // Row count for row t: words [t*8, t*8+8)
#pragma unroll
        for (int k = 0; k < 8; ++k) r += __popc(w[t * 8 + k]);
        rcs[t] = (float)r;
        // Column count for column t: bit (t&31) of word i*8 + (t>>5), rows i
        const int wsel = t >> 5;
        const int bsel = t & 31;
        for (int i = 0; i < NB; ++i) c += (w[i * 8 + wsel] >> bsel) & 1;
    }
    __syncthreads();
    float S = 0.0f;
    if (t < NB) {
        for (int i = 0; i < NB; ++i) S += rcs[i];
        // mi = -log(S) - ( sum_i rc_i*log(rc_i/S) + sum_j cc_j*log(cc_j/S) ) / S
        // (eps=1e-10 in the reference denom perturbs mi by <1e-5; << 2e-2 tol)
        if (r > 0) partial += (float)r * logf((float)r / S);
        if (c > 0) partial += (float)c * logf((float)c / S);
        for (int off = 32; off > 0; off >>= 1) partial += __shfl_down(partial, off, 64);
        if ((t & 63) == 0) red[t >> 6] = partial;
    }
    __syncthreads();
    if (t == 0) {
        float B = red[0] + red[1] + red[2] + red[3];
        float mi = -logf(S) - B / S;
        out[0] = 1.0f - tanhf(mi);
    }
}

__device__ __forceinline__ void hist_body(const float* __restrict__ x,
                                          const float* __restrict__ y,
                                          unsigned int* bm, int n, int t) {
    const int n4 = n >> 2;
    const float4* __restrict__ x4 = (const float4*)x;
    const float4* __restrict__ y4 = (const float4*)y;
    const int nth = gridDim.x * blockDim.x;
    int i = blockIdx.x * blockDim.x + t;
    // Unroll-3: 6 independent float4 loads in flight per thread (MLP).
    for (; i + 2 * nth < n4; i += 3 * nth) {
        float4 a0 = x4[i];           float4 b0 = y4[i];
        float4 a1 = x4[i + nth];     float4 b1 = y4[i + nth];
        float4 a2 = x4[i + 2 * nth]; float4 b2 = y4[i + 2 * nth];
        set_bin(bm, a0.x, b0.x); set_bin(bm, a0.y, b0.y);
        set_bin(bm, a0.z, b0.z); set_bin(bm, a0.w, b0.w);
        set_bin(bm, a1.x, b1.x); set_bin(bm, a1.y, b1.y);
        set_bin(bm, a1.z, b1.z); set_bin(bm, a1.w, b1.w);
        set_bin(bm, a2.x, b2.x); set_bin(bm, a2.y, b2.y);
        set_bin(bm, a2.z, b2.z); set_bin(bm, a2.w, b2.w);
    }
    for (; i < n4; i += nth) {
        float4 a = x4[i]; float4 b = y4[i];
        set_bin(bm, a.x, b.x); set_bin(bm, a.y, b.y);
        set_bin(bm, a.z, b.z); set_bin(bm, a.w, b.w);
    }
    for (int j = (n4 << 2) + blockIdx.x * blockDim.x + t; j < n; j += nth) {
        set_bin(bm, x[j], y[j]);
    }
}

// ---------------- main path ----------------

__global__ __launch_bounds__(HTHREADS, 2) void hist_slices(const float* __restrict__ x,
                                                           const float* __restrict__ y,
                                                           unsigned int* __restrict__ ws,
                                                           int n) {
    __shared__ unsigned int bm[BM_WORDS];
    const int t = threadIdx.x;
    if (blockIdx.x == 0 && t == 0) ws[SL_WORDS + BM_WORDS] = 0u;  // arrival counter
    for (int k = t; k < BM_WORDS; k += HTHREADS) bm[k] = 0u;
    __syncthreads();

    hist_body(x, y, bm, n, t);
    __syncthreads();

    // Publish private bitmap to this block's slice: plain coalesced uint4 stores.
    uint4 v;
    v.x = bm[4 * t];     v.y = bm[4 * t + 1];
    v.z = bm[4 * t + 2]; v.w = bm[4 * t + 3];
    ((uint4*)(ws + (size_t)blockIdx.x * BM_WORDS))[t] = v;
}

__global__ __launch_bounds__(RTHREADS) void reduce_finalize(unsigned int* __restrict__ ws,
                                                            float* __restrict__ out) {
    __shared__ uint4 p4[RTHREADS];
    __shared__ unsigned int w[BM_WORDS];
    __shared__ float rcs[NB];
    __shared__ float red[8];
    __shared__ unsigned int ticket;
    const int t = threadIdx.x;
    const int b = blockIdx.x;
    unsigned int* finalbm = ws + SL_WORDS;
    unsigned int* counter = ws + SL_WORDS + BM_WORDS;

    // Block b OR-reduces uint4 indices [b*8, b*8+8) across all HGRID slices.
    const uint4* s4 = (const uint4*)ws;          // slice s: s4[s*512 + q]
    const int q = b * 8 + (t & 7);
    uint4 v = make_uint4(0u, 0u, 0u, 0u);
#pragma unroll 4
    for (int k = 0; k < HGRID / 32; ++k) {       // 32 slices per sweep
        int s = (t >> 3) + 32 * k;
        uint4 g = s4[(size_t)s * (BM_WORDS / 4) + q];
        v.x |= g.x; v.y |= g.y; v.z |= g.z; v.w |= g.w;
    }
    p4[t] = v;
    __syncthreads();
    if (t < 8) {
        uint4 r = p4[t];
        for (int k = 1; k < 32; ++k) {
            uint4 g = p4[t + 8 * k];
            r.x |= g.x; r.y |= g.y; r.z |= g.z; r.w |= g.w;
        }
        ((uint4*)finalbm)[b * 8 + t] = r;
    }
    __syncthreads();

    // Last-block-done among RGRID blocks (counter zeroed by hist_slices).
    if (t == 0) {
        __threadfence();
        ticket = atomicAdd(counter, 1u);
    }
    __syncthreads();
    if (ticket != gridDim.x - 1) return;

    __threadfence();
    for (int k = t; k < BM_WORDS; k += RTHREADS)
        w[k] = __hip_atomic_load(&finalbm[k], __ATOMIC_RELAXED, __HIP_MEMORY_SCOPE_AGENT);
    __syncthreads();
    finalize_from_lds(w, rcs, red, t, out);
}

// ---------------- fallback path (small ws): R1-style atomic merge ----------------

__global__ void zero_kernel(unsigned int* __restrict__ bm) {
    int i = blockIdx.x * blockDim.x + threadIdx.x;
    if (i < BM_WORDS + 1) bm[i] = 0u;
}

__global__ __launch_bounds__(HTHREADS, 2) void hist_fused(const float* __restrict__ x,
                                                          const float* __restrict__ y,
                                                          unsigned int* __restrict__ gbm,
                                                          float* __restrict__ out,
                                                          int n) {
    __shared__ unsigned int bm[BM_WORDS];
    __shared__ float rcs[NB];
    __shared__ float red[8];
    __shared__ unsigned int ticket;
    const int t = threadIdx.x;

    for (int k = t; k < BM_WORDS; k += blockDim.x) bm[k] = 0u;
    __syncthreads();
    hist_body(x, y, bm, n, t);
    __syncthreads();
    for (int k = t; k < BM_WORDS; k += blockDim.x) {
        unsigned int v = bm[k];
        if (v) {
            unsigned int g = gbm[k];
            if (v & ~g) atomicOr(&gbm[k], v);
        }
    }
    __syncthreads();
    if (t == 0) {
        __threadfence();
        ticket = __hip_atomic_fetch_add(&gbm[BM_WORDS], 1u, __ATOMIC_ACQ_REL,
                                        __HIP_MEMORY_SCOPE_AGENT);
    }
    __syncthreads();
    if (ticket != gridDim.x - 1) return;
    __threadfence();
    for (int k = t; k < BM_WORDS; k += blockDim.x)
        bm[k] = __hip_atomic_load(&gbm[k], __ATOMIC_RELAXED, __HIP_MEMORY_SCOPE_AGENT);
    __syncthreads();
    finalize_from_lds(bm, rcs, red, t, out);
}

extern "C" void kernel_launch(void* const* d_in, const int* in_sizes, int n_in,
                              void* d_out, int out_size, void* d_ws, size_t ws_size,
                              hipStream_t stream) {
    const float* x = (const float*)d_in[0];  // I_complementary -> row bins
    const float* y = (const float*)d_in[1];  // I_target        -> col bins
    float* out = (float*)d_out;
    unsigned int* ws = (unsigned int*)d_ws;
    const int n = in_sizes[0];

    const size_t need = (size_t)(SL_WORDS + BM_WORDS + 1) * sizeof(unsigned int);
    if (ws_size >= need) {
        hist_slices<<<HGRID, HTHREADS, 0, stream>>>(x, y, ws, n);
        reduce_finalize<<<RGRID, RTHREADS, 0, stream>>>(ws, out);
    } else {
        zero_kernel<<<(BM_WORDS + 256) / 256, 256, 0, stream>>>(ws);
        hist_fused<<<HGRID, HTHREADS, 0, stream>>>(x, y, ws, out, n);
    }
}